// Round 11
// baseline (61.277 us; speedup 1.0000x reference)
//
#include <hip/hip_runtime.h>

// Adaptive mean thresholding: out = (x > mean11x11(x) - 2) ? 0 : 255, replicate border.
// BIT-EXACT contract (verified absmax=0.0 rounds 3-10): vertical 11-tap f32 FMA
// chain (ascending row order, weight (float)(1.0/11.0)), rounded to f32; then
// horizontal 11-tap f32 FMA chain (ascending col order); thresh = m - 2.0f;
// decision x > thresh. Replicate-border mv values are bitwise duplicates of the
// edge col's chain (synthesized by duplication, never recomputed).
//
// R11 = R8 lean structure + RPB 32->64 (halo read-amp 1.31x -> 1.16x).
// Evidence base: R9 halved VALU busy-time with zero wall-time change, and
// R4/R8/R9/R10 all plateau at 52-56us -> memory-system-bound at ~4.2 TB/s.
// Only remaining lever is traffic: fewer halo re-reads per strip.
//  - conflict-free mapping: thread t -> cols (t, t+256), all LDS lane-consecutive.
//  - register vertical ring (static shift), double-buffered mv, 1 barrier/row,
//    depth-1 preload (depth-2 measured neutral in R10).
//  - no XCD swizzle (R10: FETCH rose), no NT stores (R5: WRITE x1.9),
//    no min-waves clamp (R7: spill, FETCH x4.4).

constexpr int W   = 512;
constexpr int H   = 512;
constexpr int PAD = 5;            // (11-1)/2
constexpr int KS  = 11;
constexpr int TPB = 256;          // cols t and t+256 per thread
constexpr int RPB = 64;           // output rows per block (halo amp 74/64 = 1.16x)
constexpr int WP  = W + 2 * PAD;  // 522 padded columns

__global__ __launch_bounds__(TPB)
void AdaptiveThresholding_57904749085171_kernel(const float* __restrict__ x,
                                                float* __restrict__ out)
{
    __shared__ float mv[2][WP];    // double-buffered vertical-pass row (4.2 KB)

    const int t  = (int)threadIdx.x;
    const int cA = t;
    const int cB = t + 256;
    const int y0 = (int)blockIdx.x * RPB;
    const size_t ioff = (size_t)blockIdx.y * (size_t)(W * H);
    const float* __restrict__ xi = x + ioff;
    float* __restrict__ oi = out + ioff;
    const float wv = (float)(1.0 / 11.0);

    // Register ring: rows y-5 .. y+5 for this thread's two columns (static idx).
    float r0[KS], r1[KS];

    // ---- prologue: virtual rows y0-5 .. y0+4 -> r[0..9] ----
    #pragma unroll
    for (int k = 0; k < KS - 1; ++k) {
        int j = y0 - PAD + k;
        int src = j < 0 ? 0 : (j >= H ? H - 1 : j);
        const float* rp = xi + (size_t)src * W;
        r0[k] = rp[cA];
        r1[k] = rp[cB];
    }
    // preload virtual row y0+5
    float p0, p1;
    {
        int j = y0 + PAD;
        int src = j >= H ? H - 1 : j;
        const float* rp = xi + (size_t)src * W;
        p0 = rp[cA];
        p1 = rp[cB];
    }

    for (int y = y0; y < y0 + RPB; ++y) {
        // complete the ring: r[10] = row y+5 (preloaded last iteration)
        r0[KS - 1] = p0;
        r1[KS - 1] = p1;

        // ---- issue preload of next raw row early (max latency cover) ----
        if (y + 1 < y0 + RPB) {
            int j = y + 1 + PAD;
            int src = j >= H ? H - 1 : j;
            const float* rp = xi + (size_t)src * W;
            p0 = rp[cA];
            p1 = rp[cB];
        }

        // ---- vertical f32 FMA chains (ascending row order) ----
        float a0 = 0.0f, a1 = 0.0f;
        #pragma unroll
        for (int d = 0; d < KS; ++d) {
            a0 = fmaf(r0[d], wv, a0);
            a1 = fmaf(r1[d], wv, a1);
        }

        const int pp = (y - y0) & 1;
        mv[pp][PAD + cA] = a0;                 // lane-consecutive: conflict-free
        mv[pp][PAD + cB] = a1;
        if (t == 0) {
            #pragma unroll
            for (int i = 0; i < PAD; ++i) mv[pp][i] = a0;           // == col-0 mv
        } else if (t == TPB - 1) {
            #pragma unroll
            for (int i = 0; i < PAD; ++i) mv[pp][W + PAD + i] = a1; // == col-511 mv
        }

        // center row value (row y) before shifting
        const float xv0 = r0[PAD];
        const float xv1 = r1[PAD];

        // ---- shift ring (static indices) ----
        #pragma unroll
        for (int d = 0; d < KS - 1; ++d) {
            r0[d] = r0[d + 1];
            r1[d] = r1[d + 1];
        }

        __syncthreads();   // mv[pp] visible to all waves

        // ---- horizontal f32 FMA chains (ascending col order) + decision ----
        float m0 = 0.0f, m1 = 0.0f;
        #pragma unroll
        for (int e = 0; e < KS; ++e) m0 = fmaf(mv[pp][cA + e], wv, m0);
        #pragma unroll
        for (int e = 0; e < KS; ++e) m1 = fmaf(mv[pp][cB + e], wv, m1);

        float* op = oi + (size_t)y * W;
        op[cA] = (xv0 > m0 - 2.0f) ? 0.0f : 255.0f;
        op[cB] = (xv1 > m1 - 2.0f) ? 0.0f : 255.0f;
        // no second barrier: next iter writes mv[pp^1]; mv[pp] is overwritten
        // only at iter y+2, after all threads pass barrier(y+1).
    }
}

extern "C" void kernel_launch(void* const* d_in, const int* in_sizes, int n_in,
                              void* d_out, int out_size, void* d_ws, size_t ws_size,
                              hipStream_t stream)
{
    const float* x = (const float*)d_in[0];
    float* out = (float*)d_out;
    const int n_imgs = in_sizes[0] / (W * H);   // 128

    dim3 grid(H / RPB, n_imgs);   // 8 x 128 = 1024 blocks
    dim3 block(TPB);
    AdaptiveThresholding_57904749085171_kernel<<<grid, block, 0, stream>>>(x, out);
}

// Round 12
// 53.780 us; speedup vs baseline: 1.1394x; 1.1394x over previous
//
#include <hip/hip_runtime.h>

// Adaptive mean thresholding: out = (x > mean11x11(x) - 2) ? 0 : 255, replicate border.
// BIT-EXACT contract (verified absmax=0.0 rounds 3-11): vertical 11-tap f32 FMA
// chain (ascending row order, weight (float)(1.0/11.0)), rounded to f32; then
// horizontal 11-tap f32 FMA chain (ascending col order); thresh = m - 2.0f;
// decision x > thresh. Replicate-border mv values are bitwise duplicates of the
// edge col's chain (synthesized by duplication, never recomputed).
//
// R12 = R4/R8 best structure + float2 global I/O + conflict-free LDS, together:
//  - thread t owns ADJACENT cols (2t,2t+1) -> float2 loads AND float2 stores
//    (8 B/lane, G13 sweet spot; R8's conflict-free map forced 4 B scalar I/O).
//  - even/odd SPLIT LDS layout kills the 4-way conflict R4 paid for this map:
//    padded col p -> evn[p/2] / odd[p/2]; every horizontal tap is then
//    lane-stride-4B (conflict-free), and CSE shares 10 of 12 unique taps
//    between the two columns' chains (12 LDS reads per 2 pixels, was 22).
//  - tap accumulation order remains strictly ascending col -> bit-exact.
//  - RPB=32, 2048 blocks, register vertical ring, double-buffered LDS,
//    1 barrier/row, depth-1 preload. No launch-bound clamp / NT / swizzle
//    (R7/R5/R10 lessons).

constexpr int W   = 512;
constexpr int H   = 512;
constexpr int PAD = 5;            // (11-1)/2
constexpr int KS  = 11;
constexpr int TPB = 256;          // cols 2t, 2t+1 per thread
constexpr int RPB = 32;           // output rows per block
constexpr int HC  = (W + 2 * PAD) / 2;   // 261 entries per parity array

__global__ __launch_bounds__(TPB)
void AdaptiveThresholding_57904749085171_kernel(const float* __restrict__ x,
                                                float* __restrict__ out)
{
    __shared__ float evn[2][HC];   // padded col 2c   -> evn[buf][c]
    __shared__ float odd[2][HC];   // padded col 2c+1 -> odd[buf][c]

    const int t  = (int)threadIdx.x;
    const int c0 = 2 * t;          // first owned real column
    const int y0 = (int)blockIdx.x * RPB;
    const size_t ioff = (size_t)blockIdx.y * (size_t)(W * H);
    const float* __restrict__ xi = x + ioff;
    float* __restrict__ oi = out + ioff;
    const float wv = (float)(1.0 / 11.0);

    // Register ring: rows y-5 .. y+5 for cols c0, c0+1 (static indices).
    float r0[KS], r1[KS];

    // ---- prologue: virtual rows y0-5 .. y0+4 -> r[0..9] (float2 loads) ----
    #pragma unroll
    for (int k = 0; k < KS - 1; ++k) {
        int j = y0 - PAD + k;
        int src = j < 0 ? 0 : (j >= H ? H - 1 : j);
        const float2 v = *(const float2*)(xi + (size_t)src * W + c0);
        r0[k] = v.x; r1[k] = v.y;
    }
    float p0, p1;
    {
        int j = y0 + PAD;
        int src = j >= H ? H - 1 : j;
        const float2 v = *(const float2*)(xi + (size_t)src * W + c0);
        p0 = v.x; p1 = v.y;
    }

    for (int y = y0; y < y0 + RPB; ++y) {
        r0[KS - 1] = p0;
        r1[KS - 1] = p1;

        // ---- preload next raw row early ----
        if (y + 1 < y0 + RPB) {
            int j = y + 1 + PAD;
            int src = j >= H ? H - 1 : j;
            const float2 v = *(const float2*)(xi + (size_t)src * W + c0);
            p0 = v.x; p1 = v.y;
        }

        // ---- vertical f32 FMA chains (ascending row order) ----
        float a0 = 0.0f, a1 = 0.0f;
        #pragma unroll
        for (int d = 0; d < KS; ++d) {
            a0 = fmaf(r0[d], wv, a0);
            a1 = fmaf(r1[d], wv, a1);
        }

        const int pp = (y - y0) & 1;
        // padded index of col c0 is 2t+5 (odd) -> odd[t+2]; col c0+1 is 2t+6 -> evn[t+3]
        odd[pp][t + 2] = a0;               // lane-stride 4B: conflict-free
        evn[pp][t + 3] = a1;
        if (t == 0) {                      // padded 0..4 = mv(col 0) = a0
            evn[pp][0] = a0; odd[pp][0] = a0;
            evn[pp][1] = a0; odd[pp][1] = a0;
            evn[pp][2] = a0;
        } else if (t == TPB - 1) {         // padded 517..521 = mv(col 511) = a1
            odd[pp][258] = a1; evn[pp][259] = a1;
            odd[pp][259] = a1; evn[pp][260] = a1;
            odd[pp][260] = a1;
        }

        // center row values before shifting
        const float xv0 = r0[PAD];
        const float xv1 = r1[PAD];

        // ---- shift ring (static indices) ----
        #pragma unroll
        for (int d = 0; d < KS - 1; ++d) {
            r0[d] = r0[d + 1];
            r1[d] = r1[d + 1];
        }

        __syncthreads();

        // ---- horizontal chains, ascending col order, split-layout taps ----
        // col c0 = 2t: padded taps 2t+0..2t+10
        float m0 = 0.0f;
        m0 = fmaf(evn[pp][t    ], wv, m0);   // padded 2t
        m0 = fmaf(odd[pp][t    ], wv, m0);   // 2t+1
        m0 = fmaf(evn[pp][t + 1], wv, m0);   // 2t+2
        m0 = fmaf(odd[pp][t + 1], wv, m0);   // 2t+3
        m0 = fmaf(evn[pp][t + 2], wv, m0);   // 2t+4
        m0 = fmaf(odd[pp][t + 2], wv, m0);   // 2t+5
        m0 = fmaf(evn[pp][t + 3], wv, m0);   // 2t+6
        m0 = fmaf(odd[pp][t + 3], wv, m0);   // 2t+7
        m0 = fmaf(evn[pp][t + 4], wv, m0);   // 2t+8
        m0 = fmaf(odd[pp][t + 4], wv, m0);   // 2t+9
        m0 = fmaf(evn[pp][t + 5], wv, m0);   // 2t+10
        // col c0+1 = 2t+1: padded taps 2t+1..2t+11
        float m1 = 0.0f;
        m1 = fmaf(odd[pp][t    ], wv, m1);   // 2t+1
        m1 = fmaf(evn[pp][t + 1], wv, m1);   // 2t+2
        m1 = fmaf(odd[pp][t + 1], wv, m1);   // 2t+3
        m1 = fmaf(evn[pp][t + 2], wv, m1);   // 2t+4
        m1 = fmaf(odd[pp][t + 2], wv, m1);   // 2t+5
        m1 = fmaf(evn[pp][t + 3], wv, m1);   // 2t+6
        m1 = fmaf(odd[pp][t + 3], wv, m1);   // 2t+7
        m1 = fmaf(evn[pp][t + 4], wv, m1);   // 2t+8
        m1 = fmaf(odd[pp][t + 4], wv, m1);   // 2t+9
        m1 = fmaf(evn[pp][t + 5], wv, m1);   // 2t+10
        m1 = fmaf(odd[pp][t + 5], wv, m1);   // 2t+11

        float2 o;
        o.x = (xv0 > m0 - 2.0f) ? 0.0f : 255.0f;
        o.y = (xv1 > m1 - 2.0f) ? 0.0f : 255.0f;
        *(float2*)(oi + (size_t)y * W + c0) = o;
        // one barrier per iter: next iter writes buf pp^1; buf pp is only
        // rewritten at iter y+2, after all threads pass barrier(y+1).
    }
}

extern "C" void kernel_launch(void* const* d_in, const int* in_sizes, int n_in,
                              void* d_out, int out_size, void* d_ws, size_t ws_size,
                              hipStream_t stream)
{
    const float* x = (const float*)d_in[0];
    float* out = (float*)d_out;
    const int n_imgs = in_sizes[0] / (W * H);   // 128

    dim3 grid(H / RPB, n_imgs);   // 16 x 128 = 2048 blocks
    dim3 block(TPB);
    AdaptiveThresholding_57904749085171_kernel<<<grid, block, 0, stream>>>(x, out);
}